// Round 3
// baseline (554.012 us; speedup 1.0000x reference)
//
#include <hip/hip_runtime.h>

#define N_NODES 200000
#define DIM 480            // 120 float4 per row
#define N_SEG 4096
#define VEC (DIM / 4)      // 120
#define CHUNK 8            // rows in flight per wave in gather

// 1) Fused zero + histogram + exclusive scan, single workgroup of 1024.
//    LDS histogram (16 KB) built with LDS atomics from int4 label loads,
//    then Hillis-Steele scan over 1024 partials (4 entries/thread).
__global__ __launch_bounds__(1024) void hist_scan_kernel(
    const int* __restrict__ labels,
    int* __restrict__ counts,
    int* __restrict__ cursor) {
    __shared__ int lcnt[N_SEG];   // 16 KB
    __shared__ int part[1024];    // 4 KB
    int t = threadIdx.x;

    for (int i = t; i < N_SEG; i += 1024) lcnt[i] = 0;
    __syncthreads();

    // 200000 labels = 50000 int4, 1024 threads -> 49 iterations
    const int4* lab4 = (const int4*)labels;
    const int n4 = N_NODES / 4;   // 50000, N_NODES % 4 == 0
    for (int i = t; i < n4; i += 1024) {
        int4 L = lab4[i];
        atomicAdd(&lcnt[L.x], 1);
        atomicAdd(&lcnt[L.y], 1);
        atomicAdd(&lcnt[L.z], 1);
        atomicAdd(&lcnt[L.w], 1);
    }
    __syncthreads();

    // scan: each thread owns 4 consecutive histogram entries
    int base = t * 4;
    int l0 = lcnt[base], l1 = lcnt[base + 1], l2 = lcnt[base + 2], l3 = lcnt[base + 3];
    part[t] = l0 + l1 + l2 + l3;
    __syncthreads();
    for (int off = 1; off < 1024; off <<= 1) {
        int add = (t >= off) ? part[t - off] : 0;
        __syncthreads();
        part[t] += add;
        __syncthreads();
    }
    int excl = (t == 0) ? 0 : part[t - 1];
    counts[base]     = l0;
    counts[base + 1] = l1;
    counts[base + 2] = l2;
    counts[base + 3] = l3;
    cursor[base]     = excl;
    cursor[base + 1] = excl + l0;
    cursor[base + 2] = excl + l0 + l1;
    cursor[base + 3] = excl + l0 + l1 + l2;
}

// 2) counting-sort scatter: sorted_idx[pos] = node index
//    afterwards cursor[s] == segment end offset
__global__ void scatter_kernel(const int* __restrict__ labels,
                               int* __restrict__ cursor,
                               int* __restrict__ sorted_idx, int n) {
    int i = blockIdx.x * blockDim.x + threadIdx.x;
    if (i < n) {
        int pos = atomicAdd(&cursor[labels[i]], 1);
        sorted_idx[pos] = i;
    }
}

// 3) per-segment gather + mean, 8 rows in flight per iteration.
__global__ __launch_bounds__(128) void gather_mean_kernel(
    const float* __restrict__ x,
    const int* __restrict__ sorted_idx,
    const int* __restrict__ counts,
    const int* __restrict__ cursor,
    float* __restrict__ out) {
    int s = blockIdx.x;
    int cnt = counts[s];
    int end = cursor[s];
    int start = end - cnt;
    int t = threadIdx.x;
    if (t >= VEC) return;

    float4 acc = make_float4(0.f, 0.f, 0.f, 0.f);
    if (cnt > 0) {
        for (int j = start; j < end; j += CHUNK) {
            int   idx[CHUNK];
            float w[CHUNK];
#pragma unroll
            for (int k = 0; k < CHUNK; ++k) {
                int jj = j + k;
                w[k]   = (jj < end) ? 1.0f : 0.0f;
                idx[k] = sorted_idx[(jj < end) ? jj : start];
            }
            float4 v[CHUNK];
#pragma unroll
            for (int k = 0; k < CHUNK; ++k) {
                const float4* row = (const float4*)(x + (size_t)idx[k] * DIM);
                v[k] = row[t];
            }
#pragma unroll
            for (int k = 0; k < CHUNK; ++k) {
                acc.x = fmaf(w[k], v[k].x, acc.x);
                acc.y = fmaf(w[k], v[k].y, acc.y);
                acc.z = fmaf(w[k], v[k].z, acc.z);
                acc.w = fmaf(w[k], v[k].w, acc.w);
            }
        }
    }
    float inv = (cnt > 0) ? (1.0f / (float)cnt) : 0.0f;
    float4 r = make_float4(acc.x * inv, acc.y * inv, acc.z * inv, acc.w * inv);
    ((float4*)(out + (size_t)s * DIM))[t] = r;
}

extern "C" void kernel_launch(void* const* d_in, const int* in_sizes, int n_in,
                              void* d_out, int out_size, void* d_ws, size_t ws_size,
                              hipStream_t stream) {
    const float* x      = (const float*)d_in[0];
    const int*   labels = (const int*)d_in[1];
    float* out = (float*)d_out;

    // workspace layout: counts[4096] | cursor[4096] | sorted_idx[200000]
    int* counts     = (int*)d_ws;
    int* cursor     = counts + N_SEG;
    int* sorted_idx = cursor + N_SEG;

    hist_scan_kernel<<<1, 1024, 0, stream>>>(labels, counts, cursor);
    scatter_kernel<<<(N_NODES + 255) / 256, 256, 0, stream>>>(labels, cursor,
                                                              sorted_idx, N_NODES);
    gather_mean_kernel<<<N_SEG, 128, 0, stream>>>(x, sorted_idx, counts, cursor, out);
}